// Round 3
// baseline (317.134 us; speedup 1.0000x reference)
//
#include <hip/hip_runtime.h>

#define NROWS 8192
#define DDIM  256
#define BM    128
#define BN    128
#define BK    64

typedef __attribute__((ext_vector_type(8))) short bf16x8;
typedef __attribute__((ext_vector_type(4))) float f32x4;

// round-to-nearest-even f32 -> bf16 bits (inputs are finite gaussians; no NaN path)
static __device__ __forceinline__ unsigned short f2bf(float f) {
    unsigned u = __float_as_uint(f);
    u += 0x7fff + ((u >> 16) & 1);
    return (unsigned short)(u >> 16);
}

// Pass 1: f32 -> bf16 conversion + per-row sum of squares.
__global__ __launch_bounds__(256) void rbf_prep_kernel(
    const float* __restrict__ x, const float* __restrict__ y,
    unsigned short* __restrict__ xb, unsigned short* __restrict__ yb,
    float* __restrict__ xsq, float* __restrict__ ysq)
{
    const int lane = threadIdx.x & 63;
    const int wid  = threadIdx.x >> 6;
    int row = blockIdx.x * 4 + wid;            // 0..16383
    const float* src; unsigned short* dst; float* sq; int r;
    if (row < NROWS) { src = x; dst = xb; sq = xsq; r = row; }
    else             { src = y; dst = yb; sq = ysq; r = row - NROWS; }

    const float4 v = ((const float4*)(src + (size_t)r * DDIM))[lane];
    ushort4 b;
    b.x = f2bf(v.x); b.y = f2bf(v.y); b.z = f2bf(v.z); b.w = f2bf(v.w);
    ((ushort4*)(dst + (size_t)r * DDIM))[lane] = b;

    float s = v.x * v.x + v.y * v.y + v.z * v.z + v.w * v.w;
    #pragma unroll
    for (int o = 32; o > 0; o >>= 1) s += __shfl_down(s, o);
    if (lane == 0) sq[r] = s;
}

// Pass 2: C = Xb * Yb^T via bf16 MFMA, epilogue exp(-(xsq + ysq - 2C)).
// 128x128 tile, BK=64, 4 waves 2x2. T3-minimum 2-phase pipeline:
// double-buffered LDS; next tile's global_load_lds issued BEFORE current
// tile's MFMA, so the vmcnt(0) drain at __syncthreads is hidden under compute.
__global__ __launch_bounds__(256) void rbf_gemm_kernel(
    const unsigned short* __restrict__ A,   // 8192 x 256 bf16 (X)
    const unsigned short* __restrict__ B,   // 8192 x 256 bf16 (Y)
    const float* __restrict__ xsq, const float* __restrict__ ysq,
    float* __restrict__ out)
{
    __shared__ unsigned short As[2][BM * BK];   // 2 x 16 KB
    __shared__ unsigned short Bs[2][BN * BK];   // 2 x 16 KB

    const int t    = threadIdx.x;
    const int lane = t & 63;
    const int wid  = t >> 6;
    const int wr   = wid >> 1;          // wave row (0..1) -> 64-row slab of X
    const int wc   = wid & 1;           // wave col (0..1) -> 64-col slab of Y
    const int brow = blockIdx.y * BM;
    const int bcol = blockIdx.x * BN;

    f32x4 acc[4][4] = {};               // [m][n] transposed 16x16 fragments

    const int rr = lane & 15;           // row within fragment (both operands)
    const int kq = lane >> 4;           // k-quarter

    // stage tile kt into buffer buf (8 x global_load_lds width-16 per thread)
    #define STAGE(buf, kt)                                                              \
        _Pragma("unroll")                                                               \
        for (int i = 0; i < 4; ++i) {                                                   \
            const int idx = (i * 256 + t) * 8;                                          \
            const int r   = idx >> 6;                                                   \
            const int c   = idx & 63;                                                   \
            __builtin_amdgcn_global_load_lds(                                           \
                (const __attribute__((address_space(1))) unsigned int*)(A + (size_t)(brow + r) * DDIM + (kt) + c), \
                (__attribute__((address_space(3))) unsigned int*)(&As[buf][idx]), 16, 0, 0); \
            __builtin_amdgcn_global_load_lds(                                           \
                (const __attribute__((address_space(1))) unsigned int*)(B + (size_t)(bcol + r) * DDIM + (kt) + c), \
                (__attribute__((address_space(3))) unsigned int*)(&Bs[buf][idx]), 16, 0, 0); \
        }

    #define COMPUTE(buf)                                                                \
        _Pragma("unroll")                                                               \
        for (int ks = 0; ks < 2; ++ks) {                                                \
            bf16x8 a[4], b[4];                                                          \
            const int ko = ks * 32 + kq * 8;                                            \
            _Pragma("unroll")                                                           \
            for (int m = 0; m < 4; ++m)                                                 \
                a[m] = *(const bf16x8*)(&As[buf][(wr * 64 + m * 16 + rr) * BK + ko]);   \
            _Pragma("unroll")                                                           \
            for (int n = 0; n < 4; ++n)                                                 \
                b[n] = *(const bf16x8*)(&Bs[buf][(wc * 64 + n * 16 + rr) * BK + ko]);   \
            _Pragma("unroll")                                                           \
            for (int m = 0; m < 4; ++m)                                                 \
                _Pragma("unroll")                                                       \
                for (int n = 0; n < 4; ++n)                                             \
                    acc[m][n] = __builtin_amdgcn_mfma_f32_16x16x32_bf16(b[n], a[m], acc[m][n], 0, 0, 0); \
        }

    STAGE(0, 0)
    __syncthreads();                 // prologue drain (only exposed wait)

    STAGE(1, 64)                     // prefetch kt=64
    COMPUTE(0)                       // compute kt=0 while loads fly
    __syncthreads();                 // drain: loads have had a full MFMA phase

    STAGE(0, 128)
    COMPUTE(1)
    __syncthreads();

    STAGE(1, 192)
    COMPUTE(0)
    __syncthreads();

    COMPUTE(1)                       // last tile, no prefetch

    // epilogue: swapped-operand fragment => lane's X row = lane&15,
    // Y cols = (lane>>4)*4 + {0..3} -> float4 stores
    const int cl = lane & 15;
    const int rq = lane >> 4;
    #pragma unroll
    for (int m = 0; m < 4; ++m) {
        const int row = brow + wr * 64 + m * 16 + cl;
        const float xsv = xsq[row];
        float* orow = out + (size_t)row * NROWS;
        #pragma unroll
        for (int n = 0; n < 4; ++n) {
            const int col = bcol + wc * 64 + n * 16 + rq * 4;
            const float4 ysv = *(const float4*)(ysq + col);
            float4 o;
            o.x = __expf(-fmaxf(xsv + ysv.x - 2.0f * acc[m][n][0], 0.0f));
            o.y = __expf(-fmaxf(xsv + ysv.y - 2.0f * acc[m][n][1], 0.0f));
            o.z = __expf(-fmaxf(xsv + ysv.z - 2.0f * acc[m][n][2], 0.0f));
            o.w = __expf(-fmaxf(xsv + ysv.w - 2.0f * acc[m][n][3], 0.0f));
            *(float4*)(orow + col) = o;
        }
    }
}

extern "C" void kernel_launch(void* const* d_in, const int* in_sizes, int n_in,
                              void* d_out, int out_size, void* d_ws, size_t ws_size,
                              hipStream_t stream) {
    const float* x = (const float*)d_in[0];
    const float* y = (const float*)d_in[1];
    float* out = (float*)d_out;

    // ws layout: xb (4 MiB) | yb (4 MiB) | xsq (32 KiB) | ysq (32 KiB)
    unsigned short* xb = (unsigned short*)d_ws;
    unsigned short* yb = xb + (size_t)NROWS * DDIM;
    float* xsq = (float*)(yb + (size_t)NROWS * DDIM);
    float* ysq = xsq + NROWS;

    rbf_prep_kernel<<<dim3((2 * NROWS) / 4), 256, 0, stream>>>(x, y, xb, yb, xsq, ysq);
    rbf_gemm_kernel<<<dim3(NROWS / BN, NROWS / BM), 256, 0, stream>>>(xb, yb, xsq, ysq, out);
}

// Round 6
// 304.460 us; speedup vs baseline: 1.0416x; 1.0416x over previous
//
#include <hip/hip_runtime.h>

#define NROWS 8192
#define DDIM  256
#define BM    128
#define BN    128
#define BK    64

typedef __attribute__((ext_vector_type(8))) short bf16x8;
typedef __attribute__((ext_vector_type(4))) float f32x4;

// round-to-nearest-even f32 -> bf16 bits (inputs are finite gaussians; no NaN path)
static __device__ __forceinline__ unsigned short f2bf(float f) {
    unsigned u = __float_as_uint(f);
    u += 0x7fff + ((u >> 16) & 1);
    return (unsigned short)(u >> 16);
}

// Pass 1: f32 -> bf16 conversion + per-row sum of squares.
__global__ __launch_bounds__(256) void rbf_prep_kernel(
    const float* __restrict__ x, const float* __restrict__ y,
    unsigned short* __restrict__ xb, unsigned short* __restrict__ yb,
    float* __restrict__ xsq, float* __restrict__ ysq)
{
    const int lane = threadIdx.x & 63;
    const int wid  = threadIdx.x >> 6;
    int row = blockIdx.x * 4 + wid;            // 0..16383
    const float* src; unsigned short* dst; float* sq; int r;
    if (row < NROWS) { src = x; dst = xb; sq = xsq; r = row; }
    else             { src = y; dst = yb; sq = ysq; r = row - NROWS; }

    const float4 v = ((const float4*)(src + (size_t)r * DDIM))[lane];
    ushort4 b;
    b.x = f2bf(v.x); b.y = f2bf(v.y); b.z = f2bf(v.z); b.w = f2bf(v.w);
    ((ushort4*)(dst + (size_t)r * DDIM))[lane] = b;

    float s = v.x * v.x + v.y * v.y + v.z * v.z + v.w * v.w;
    #pragma unroll
    for (int o = 32; o > 0; o >>= 1) s += __shfl_down(s, o);
    if (lane == 0) sq[r] = s;
}

// Pass 2: C = Xb * Yb^T via bf16 MFMA, epilogue exp(-(xsq + ysq - 2C)).
// Single-buffered 128x128 tile, BK=64, 4 waves 2x2 (R2 structure — dbuf
// regressed via occupancy: 64KB LDS -> 2 blocks/CU; implicit wave-level
// overlap across resident blocks already hides the staging drain).
// Output stores are NONTEMPORAL (via ext_vector f32x4 — HIP float4 is a
// class type that __builtin_nontemporal_store rejects): 256MB stream,
// never re-read — keep it from evicting L2/L3-resident input panels.
__global__ __launch_bounds__(256) void rbf_gemm_kernel(
    const unsigned short* __restrict__ A,   // 8192 x 256 bf16 (X)
    const unsigned short* __restrict__ B,   // 8192 x 256 bf16 (Y)
    const float* __restrict__ xsq, const float* __restrict__ ysq,
    float* __restrict__ out)
{
    __shared__ unsigned short As[BM * BK];
    __shared__ unsigned short Bs[BN * BK];

    const int t    = threadIdx.x;
    const int lane = t & 63;
    const int wid  = t >> 6;
    const int wr   = wid >> 1;          // wave row (0..1) -> 64-row slab of X
    const int wc   = wid & 1;           // wave col (0..1) -> 64-col slab of Y
    const int brow = blockIdx.y * BM;
    const int bcol = blockIdx.x * BN;

    f32x4 acc[4][4] = {};               // [m][n] transposed 16x16 fragments

    const int rr = lane & 15;           // row within fragment (both operands)
    const int kq = lane >> 4;           // k-quarter

    for (int kt = 0; kt < DDIM; kt += BK) {
        #pragma unroll
        for (int i = 0; i < 4; ++i) {
            const int idx = (i * 256 + t) * 8;      // element index in tile
            const int r   = idx >> 6;               // tile row
            const int c   = idx & 63;               // tile col (k)
            __builtin_amdgcn_global_load_lds(
                (const __attribute__((address_space(1))) unsigned int*)(A + (size_t)(brow + r) * DDIM + kt + c),
                (__attribute__((address_space(3))) unsigned int*)(As + idx), 16, 0, 0);
            __builtin_amdgcn_global_load_lds(
                (const __attribute__((address_space(1))) unsigned int*)(B + (size_t)(bcol + r) * DDIM + kt + c),
                (__attribute__((address_space(3))) unsigned int*)(Bs + idx), 16, 0, 0);
        }
        __syncthreads();

        #pragma unroll
        for (int ks = 0; ks < 2; ++ks) {
            bf16x8 a[4], b[4];
            const int ko = ks * 32 + kq * 8;
            #pragma unroll
            for (int m = 0; m < 4; ++m)
                a[m] = *(const bf16x8*)(As + (wr * 64 + m * 16 + rr) * BK + ko);
            #pragma unroll
            for (int n = 0; n < 4; ++n)
                b[n] = *(const bf16x8*)(Bs + (wc * 64 + n * 16 + rr) * BK + ko);
            #pragma unroll
            for (int m = 0; m < 4; ++m)
                #pragma unroll
                for (int n = 0; n < 4; ++n)
                    acc[m][n] = __builtin_amdgcn_mfma_f32_16x16x32_bf16(b[n], a[m], acc[m][n], 0, 0, 0);
        }
        __syncthreads();
    }

    // epilogue: swapped-operand fragment => lane's X row = lane&15,
    // Y cols = (lane>>4)*4 + {0..3} -> nontemporal f32x4 stores
    const int cl = lane & 15;
    const int rq = lane >> 4;
    #pragma unroll
    for (int m = 0; m < 4; ++m) {
        const int row = brow + wr * 64 + m * 16 + cl;
        const float xsv = xsq[row];
        float* orow = out + (size_t)row * NROWS;
        #pragma unroll
        for (int n = 0; n < 4; ++n) {
            const int col = bcol + wc * 64 + n * 16 + rq * 4;
            const float4 ysv = *(const float4*)(ysq + col);
            f32x4 o;
            o[0] = __expf(-fmaxf(xsv + ysv.x - 2.0f * acc[m][n][0], 0.0f));
            o[1] = __expf(-fmaxf(xsv + ysv.y - 2.0f * acc[m][n][1], 0.0f));
            o[2] = __expf(-fmaxf(xsv + ysv.z - 2.0f * acc[m][n][2], 0.0f));
            o[3] = __expf(-fmaxf(xsv + ysv.w - 2.0f * acc[m][n][3], 0.0f));
            __builtin_nontemporal_store(o, (f32x4*)(orow + col));
        }
    }
}

extern "C" void kernel_launch(void* const* d_in, const int* in_sizes, int n_in,
                              void* d_out, int out_size, void* d_ws, size_t ws_size,
                              hipStream_t stream) {
    const float* x = (const float*)d_in[0];
    const float* y = (const float*)d_in[1];
    float* out = (float*)d_out;

    // ws layout: xb (4 MiB) | yb (4 MiB) | xsq (32 KiB) | ysq (32 KiB)
    unsigned short* xb = (unsigned short*)d_ws;
    unsigned short* yb = xb + (size_t)NROWS * DDIM;
    float* xsq = (float*)(yb + (size_t)NROWS * DDIM);
    float* ysq = xsq + NROWS;

    rbf_prep_kernel<<<dim3((2 * NROWS) / 4), 256, 0, stream>>>(x, y, xb, yb, xsq, ysq);
    rbf_gemm_kernel<<<dim3(NROWS / BN, NROWS / BM), 256, 0, stream>>>(xb, yb, xsq, ysq, out);
}